// Round 1
// baseline (121.712 us; speedup 1.0000x reference)
//
#include <hip/hip_runtime.h>

// Problem constants (from setup_inputs): bs=32, C=128, Gn=256, S=16
#define GQ   8192          // total groups = bs*Gn
#define CCH  128           // channels
#define FSTR 20            // LDS row stride (floats) for F: 16-B aligned + bank-quad permutation

// LDS layout (floats):
//   [0,2560)      F: 128 rows x 20   (aliased by R: up to 32 rows x 68 = 2176 during pair phase)
//   [2560,2740)   Wm: 9 rows x 20    (bucket weight matrix, cols 0..15 used)
//   [2740,2821)   SIMM: 9x9 sim matrix
//   [2821,2837)   LI: per-row li values
//   [2837,2853)   IDXL: 16 seed indices (as int)

__global__ __launch_bounds__(64, 4) void group_loss_kernel(
    const int*   __restrict__ labs,   // [G*16]
    const float* __restrict__ feats,  // [32,128,256,16]
    const int*   __restrict__ idxs,   // [G*16]
    const float* __restrict__ ctx,    // [128]
    float* __restrict__ ws0, float* __restrict__ ws1)
{
    __shared__ float SH[2853];
    float* F    = SH;
    float* Wm   = SH + 2560;
    float* SIMM = SH + 2740;
    float* LI   = SH + 2821;
    int*   IDXL = (int*)(SH + 2837);

    const int l   = threadIdx.x;
    const int blk = blockIdx.x;
    // XCD swizzle: contiguous 1024-group chunk per XCD (blk%8 -> XCD heuristic)
    const int g  = ((blk & 7) << 10) | (blk >> 3);
    const int b  = g >> 8;
    const int gn = g & 255;
    const int fbase = b * (CCH * 256 * 16) + gn * 16;   // element (c,s) at fbase + c*4096 + s

    // ---- stage seed indices, load own label --------------------------------
    if (l < 16) IDXL[l] = idxs[g * 16 + l];
    int mylab = 0;
    if (l < 16) mylab = labs[g * 16 + l];
    __syncthreads();

    // ---- u = count of distinct seed indices (positional first-occurrence) --
    const int myidx = IDXL[l & 15];
    bool dup = false;
    #pragma unroll
    for (int j = 0; j < 15; ++j)
        dup = dup || ((j < l) && (IDXL[j] == myidx));
    const unsigned long long firstm = __ballot((l < 16) && !dup);
    const int u = __popcll(firstm);

    // ---- bucket membership via ballots (bucket 0 = label -1) ---------------
    const bool valid = l < u;                      // lanes >=16 auto-invalid (u<=16)
    const int bid = valid ? (mylab + 1) : 255;

    unsigned long long memb[9];
    int cnt[9];
    #pragma unroll
    for (int r = 0; r < 9; ++r) {
        memb[r] = __ballot(bid == r);
        cnt[r]  = __popcll(memb[r]);
    }
    const bool has_bg = cnt[0] > 0;
    int fg_count = 0;
    #pragma unroll
    for (int r = 1; r < 9; ++r) fg_count += (cnt[r] > 0) ? 1 : 0;
    int pm = 0;                                    // fg-row presence bitmask
    #pragma unroll
    for (int r = 1; r < 9; ++r) pm |= (cnt[r] > 0) ? (1 << r) : 0;

    // ---- build weight matrix W[9][16]: one-hot/cnt (invc folded in) --------
    #pragma unroll
    for (int r = 0; r < 9; ++r) {
        float w = 0.0f;
        if (l < 16 && ((memb[r] >> l) & 1ULL)) w = 1.0f / (float)cnt[r];
        if (r == 0 && !has_bg) w = 0.0f;           // row 0 replaced by ctx later
        if (l < 20) Wm[r * FSTR + l] = (l < 16) ? w : 0.0f;
    }

    // ---- stage features: global float4 (16 fully-used 64B segs/instr) ------
    {
        const float* gp = feats + fbase;
        #pragma unroll
        for (int i = 0; i < 8; ++i) {
            const int c = i * 16 + (l >> 2);
            const int q = l & 3;
            float4 v = *(const float4*)(gp + c * 4096 + q * 4);
            *(float4*)(&F[c * FSTR + q * 4]) = v;
        }
    }
    __syncthreads();

    // ---- each lane owns channels c0=l, c1=l+64: read columns (conflict-free)
    const int c0 = l, c1 = l + 64;
    float4 va[4], vb[4];
    #pragma unroll
    for (int q = 0; q < 4; ++q) {
        va[q] = *(const float4*)(&F[c0 * FSTR + q * 4]);
        vb[q] = *(const float4*)(&F[c1 * FSTR + q * 4]);
    }
    const float cx0 = ctx[c0], cx1 = ctx[c1];

    // ---- M rows: m[r][c] = sum_s W[r][s] * f[s][c] -------------------------
    float m0[9], m1[9];
    #pragma unroll
    for (int r = 0; r < 9; ++r) {
        float a = 0.0f, c2 = 0.0f;
        #pragma unroll
        for (int q = 0; q < 4; ++q) {
            float4 w = *(const float4*)(&Wm[r * FSTR + q * 4]);  // broadcast read
            a  += va[q].x * w.x + va[q].y * w.y + va[q].z * w.z + va[q].w * w.w;
            c2 += vb[q].x * w.x + vb[q].y * w.y + vb[q].z * w.z + vb[q].w * w.w;
        }
        m0[r] = a; m1[r] = c2;
    }
    if (!has_bg) { m0[0] = cx0; m1[0] = cx1; }     // row 0 = context_compen

    // ---- 44 pair partials: pairs (i,j), 1<=i<=8, 0<=j<=i -------------------
    float part[44];
    {
        int p = 0;
        #pragma unroll
        for (int i = 1; i < 9; ++i)
            #pragma unroll
            for (int j = 0; j <= i; ++j) { part[p] = m0[i] * m0[j] + m1[i] * m1[j]; ++p; }
    }
    __syncthreads();   // F columns consumed; safe to alias R over F

    // ---- cross-lane pair reduction via LDS transpose (R aliases F) ---------
    // R rows padded to 68 floats so lane t's float4 reads hit all 8 bank-quads.
    #pragma unroll
    for (int pass = 0; pass < 2; ++pass) {
        const int p0 = pass * 32;
        const int np = pass ? 12 : 32;
        #pragma unroll
        for (int k = 0; k < 32; ++k)
            if (k < np) F[k * 68 + l] = part[p0 + k];
        __syncthreads();
        if (l < np) {
            const int pr = p0 + l;
            // invert pr = i(i+1)/2 - 1 + j ; 8*S_i+9 = (2i+1)^2 exact in fp32
            const int i = (int)((sqrtf(8.0f * (float)pr + 9.0f) - 1.0f) * 0.5f);
            const int j = pr - (i * (i + 1) / 2 - 1);
            float ssum = 0.0f;
            #pragma unroll
            for (int q = 0; q < 16; ++q) {
                float4 v = *(const float4*)(&F[l * 68 + q * 4]);
                ssum += v.x + v.y + v.z + v.w;
            }
            ssum *= 5.0f;                           // 1/T
            SIMM[i * 9 + j] = ssum;
            if (i != j) SIMM[j * 9 + i] = ssum;
        }
        __syncthreads();
    }

    // ---- masked logsumexp per fg row (lane r handles row r) ----------------
    float li_val = 0.0f;
    if (l >= 1 && l < 9 && ((pm >> l) & 1)) {
        float srow[9];
        #pragma unroll
        for (int j = 0; j < 9; ++j) srow[j] = SIMM[l * 9 + j];
        float vmax = srow[0];                       // col 0 always a valid instance
        #pragma unroll
        for (int j = 1; j < 9; ++j)
            if ((pm >> j) & 1) vmax = fmaxf(vmax, srow[j]);
        float se = __expf(srow[0] - vmax);
        #pragma unroll
        for (int j = 1; j < 9; ++j)
            if ((pm >> j) & 1) se += __expf(srow[j] - vmax);
        const float sdiag = SIMM[l * 9 + l];
        li_val = vmax + __logf(se) - sdiag;
    }
    if (l < 9) LI[l] = li_val;
    __syncthreads();

    if (l == 0) {
        float s = 0.0f;
        #pragma unroll
        for (int r = 1; r < 9; ++r) s += LI[r];
        const float den = (float)(fg_count > 0 ? fg_count : 1);
        ws0[g] = s / den;                           // = gl*gv (gl==0 when fg_count==0)
        ws1[g] = (fg_count > 0) ? 1.0f : 0.0f;
    }
}

// Deterministic 8192 -> 1 reduction
__global__ __launch_bounds__(256) void reduce_kernel(
    const float* __restrict__ ws0, const float* __restrict__ ws1,
    float* __restrict__ out)
{
    __shared__ float sa[256], sb[256];
    const int t = threadIdx.x;
    float a = 0.0f, b2 = 0.0f;
    for (int g = t; g < GQ; g += 256) { a += ws0[g]; b2 += ws1[g]; }
    sa[t] = a; sb[t] = b2;
    __syncthreads();
    for (int off = 128; off > 0; off >>= 1) {
        if (t < off) { sa[t] += sa[t + off]; sb[t] += sb[t + off]; }
        __syncthreads();
    }
    if (t == 0) out[0] = 0.1f * (sa[0] / sb[0]);
}

extern "C" void kernel_launch(void* const* d_in, const int* in_sizes, int n_in,
                              void* d_out, int out_size, void* d_ws, size_t ws_size,
                              hipStream_t stream) {
    const int*   labs  = (const int*)d_in[0];    // proposal_instance_mask
    const float* feats = (const float*)d_in[1];  // grouped_features
    const int*   idxs  = (const int*)d_in[2];    // grouped_indices
    const float* ctx   = (const float*)d_in[3];  // context_compen
    float* out = (float*)d_out;
    float* ws0 = (float*)d_ws;
    float* ws1 = ws0 + GQ;

    group_loss_kernel<<<GQ, 64, 0, stream>>>(labs, feats, idxs, ctx, ws0, ws1);
    reduce_kernel<<<1, 256, 0, stream>>>(ws0, ws1, out);
}